// Round 7
// baseline (91.796 us; speedup 1.0000x reference)
//
#include <hip/hip_runtime.h>

#define N_ROWS 8192
#define D_DIM  256
#define EPS    1e-6f
#define MARGIN 0.5f
#define NBLK   64                    // 8192 / 128 tiles per dim
#define NTRI   (NBLK * (NBLK + 1) / 2)   // 2080 upper-triangle blocks

typedef __bf16 bf16x8 __attribute__((ext_vector_type(8)));
typedef float  f32x4  __attribute__((ext_vector_type(4)));

// round-to-nearest-even fp32 -> bf16
__device__ inline unsigned short f2bf(float f) {
    unsigned u = __float_as_uint(f);
    return (unsigned short)((u + 0x7FFFu + ((u >> 16) & 1u)) >> 16);
}

// Prep v2 (unchanged from R5/R6 — layout verified end-to-end, absmax=0):
// chunk (rb,kb) = 1KB = rows [rb*16,+16) x k [kb*32,+32), elem (row,k) at
// lane=((k>>3)&3)*16+(row&15), j=k&7. Wave writes whole chunks coalesced.
__global__ __launch_bounds__(256)
void prep_kernel(const float* __restrict__ X,
                 unsigned short* __restrict__ Xs,
                 float* __restrict__ sq, float* __restrict__ s) {
    __shared__ float lsq[64], ls[64];
    int t = threadIdx.x;
    int w = t >> 6, l = t & 63;
    int rb = blockIdx.x;
    int row = rb * 16 + (l & 15);
    int q   = l >> 4;                      // k-quarter 0..3
    float psq = 0.f, ps = 0.f;
    for (int h = 0; h < 2; h++) {
        int kb = 2 * w + h;
        int k0 = kb * 32 + q * 8;
        const float* xp = X + (size_t)row * D_DIM + k0;
        float4 v0 = ((const float4*)xp)[0];
        float4 v1 = ((const float4*)xp)[1];
        float xv[8] = {v0.x, v0.y, v0.z, v0.w, v1.x, v1.y, v1.z, v1.w};
        for (int i = 0; i < 8; i++) { psq += xv[i] * xv[i]; ps += xv[i]; }
        unsigned w0 = (unsigned)f2bf(xv[0]) | ((unsigned)f2bf(xv[1]) << 16);
        unsigned w1 = (unsigned)f2bf(xv[2]) | ((unsigned)f2bf(xv[3]) << 16);
        unsigned w2 = (unsigned)f2bf(xv[4]) | ((unsigned)f2bf(xv[5]) << 16);
        unsigned w3 = (unsigned)f2bf(xv[6]) | ((unsigned)f2bf(xv[7]) << 16);
        *(uint4*)(Xs + (size_t)(rb * 8 + kb) * 512 + (size_t)l * 8) =
            make_uint4(w0, w1, w2, w3);
    }
    psq += __shfl_xor(psq, 16, 64); psq += __shfl_xor(psq, 32, 64);
    ps  += __shfl_xor(ps,  16, 64); ps  += __shfl_xor(ps,  32, 64);
    if (l < 16) { lsq[w * 16 + l] = psq; ls[w * 16 + l] = ps; }
    __syncthreads();
    if (t < 16) {
        float aq = 0.f, as = 0.f;
        for (int i = 0; i < 4; i++) { aq += lsq[i * 16 + t]; as += ls[i * 16 + t]; }
        sq[rb * 16 + t] = aq; s[rb * 16 + t] = as;
    }
}

// Gram + loss v3: register-direct fragment pipeline. The swizzled layout IS
// the MFMA fragment layout, so each wave loads its A/B fragments straight
// from global (lane-contiguous 16B = coalesced dwordx4) — no LDS, ZERO
// barriers in the K-loop. Register destinations let the compiler emit
// fine-grained s_waitcnt vmcnt(N) (AITER pattern) instead of the LDS-forced
// vmcnt(0)+s_barrier drain that capped R4 at ~31us. Double-buffered frags,
// fully unrolled K-loop. A-frag reuse between the 2 waves sharing wr hits L1.
__global__ __launch_bounds__(256, 3)
void gram_loss_kernel(const unsigned short* __restrict__ Xs,
                      const float* __restrict__ sq, const float* __restrict__ s,
                      const int* __restrict__ tgt,
                      float* __restrict__ partials) {
    __shared__ float wsum[4];

    // decode linear block id -> (bi, bj), bj >= bi.  f(i) = i*64 - i*(i-1)/2
    int p = blockIdx.x;
    int bi = (int)(64.5f - sqrtf(64.5f * 64.5f - 2.0f * (float)p));
    if (bi < 0) bi = 0; if (bi > 63) bi = 63;
    while ((bi + 1) * 64 - ((bi + 1) * bi) / 2 <= p) bi++;
    while (bi * 64 - (bi * (bi - 1)) / 2 > p) bi--;
    int bj = bi + (p - (bi * 64 - (bi * (bi - 1)) / 2));
    float weight = (bi == bj) ? 1.0f : 2.0f;

    int wave = threadIdx.x >> 6;
    int lane = threadIdx.x & 63;
    int wr = wave >> 1, wc = wave & 1;
    int rb0 = bi * 8 + wr * 4;                 // 4 consecutive 16-row blocks
    int cb0 = bj * 8 + wc * 4;

    // fragment (rb, kb) lives at Xs + (rb*8 + kb)*512 + lane*8  (elements)
    const unsigned short* fbase = Xs + (size_t)lane * 8;

    f32x4 acc[4][4];
    for (int r = 0; r < 4; r++)
        for (int c = 0; c < 4; c++)
            for (int e = 0; e < 4; e++) acc[r][c][e] = 0.0f;

    bf16x8 a[2][4], b[2][4];
    #pragma unroll
    for (int r = 0; r < 4; r++) {
        a[0][r] = *(const bf16x8*)(fbase + (size_t)((rb0 + r) * 8 + 0) * 512);
        b[0][r] = *(const bf16x8*)(fbase + (size_t)((cb0 + r) * 8 + 0) * 512);
    }

    #pragma unroll
    for (int kb = 0; kb < 8; kb++) {
        int cur = kb & 1, nxt = cur ^ 1;
        if (kb < 7) {
            #pragma unroll
            for (int r = 0; r < 4; r++) {
                a[nxt][r] = *(const bf16x8*)(fbase + (size_t)((rb0 + r) * 8 + kb + 1) * 512);
                b[nxt][r] = *(const bf16x8*)(fbase + (size_t)((cb0 + r) * 8 + kb + 1) * 512);
            }
        }
        #pragma unroll
        for (int r = 0; r < 4; r++)
            #pragma unroll
            for (int c = 0; c < 4; c++)
                acc[r][c] = __builtin_amdgcn_mfma_f32_16x16x32_bf16(
                    a[cur][r], b[cur][c], acc[r][c], 0, 0, 0);
    }

    // Epilogue: C/D layout col = lane&15, row = (lane>>4)*4 + e  [m89-verified]
    int rquad = (lane >> 4) * 4;
    int lcol  = lane & 15;
    float sqc[4], scv[4];
    int tc[4];
    for (int c = 0; c < 4; c++) {
        int col = (cb0 + c) * 16 + lcol;
        sqc[c] = sq[col]; scv[c] = s[col]; tc[c] = tgt[col];
    }

    float partial = 0.0f;
    const float deps2 = (float)D_DIM * EPS * EPS;
    for (int r = 0; r < 4; r++) {
        int rowbase = (rb0 + r) * 16 + rquad;
        for (int e = 0; e < 4; e++) {
            int row = rowbase + e;
            float sqr = sq[row];
            float sr  = s[row];
            int tr = tgt[row];
            for (int c = 0; c < 4; c++) {
                float g  = acc[r][c][e];
                float d2 = sqr + sqc[c] - 2.0f * g
                         + 2.0f * EPS * (sr - scv[c]) + deps2;
                partial += (tr == tc[c]) ? d2 : fmaxf(MARGIN - d2, 0.0f);
            }
        }
    }

    partial *= weight;
    for (int off = 32; off > 0; off >>= 1)
        partial += __shfl_down(partial, off, 64);
    if (lane == 0) wsum[wave] = partial;
    __syncthreads();
    if (threadIdx.x == 0)
        partials[p] = wsum[0] + wsum[1] + wsum[2] + wsum[3];
}

// Final reduce: NTRI partials -> out[0] with 1/N scale.
__global__ __launch_bounds__(256)
void reduce_kernel(const float* __restrict__ partials, float* __restrict__ out) {
    __shared__ float wsum[4];
    int t = threadIdx.x;
    float v = 0.0f;
    for (int i = t; i < NTRI; i += 256) v += partials[i];
    for (int off = 32; off > 0; off >>= 1)
        v += __shfl_down(v, off, 64);
    int wave = t >> 6, lane = t & 63;
    if (lane == 0) wsum[wave] = v;
    __syncthreads();
    if (t == 0)
        out[0] = (wsum[0] + wsum[1] + wsum[2] + wsum[3]) * (1.0f / (float)N_ROWS);
}

extern "C" void kernel_launch(void* const* d_in, const int* in_sizes, int n_in,
                              void* d_out, int out_size, void* d_ws, size_t ws_size,
                              hipStream_t stream) {
    const float* X  = (const float*)d_in[0];
    const int* tgt  = (const int*)d_in[1];   // harness passes integer inputs as int32
    float* out      = (float*)d_out;

    unsigned short* Xs = (unsigned short*)d_ws;                       // 4 MB bf16 swizzled
    float* sq = (float*)((char*)d_ws + (size_t)N_ROWS * D_DIM * 2);   // 32 KB
    float* s  = sq + N_ROWS;                                          // 32 KB
    float* partials = s + N_ROWS;                                     // ~8 KB

    prep_kernel<<<N_ROWS / 16, 256, 0, stream>>>(X, Xs, sq, s);
    gram_loss_kernel<<<NTRI, 256, 0, stream>>>(Xs, sq, s, tgt, partials);
    reduce_kernel<<<1, 256, 0, stream>>>(partials, out);
}